// Round 7
// baseline (1327.376 us; speedup 1.0000x reference)
//
#include <hip/hip_runtime.h>
#include <hip/hip_bf16.h>
#include <cstdint>
#include <cstddef>

// B=4, S=2048, D=768 single-head causal attention, fp32 I/O.
// Round 7: R6 mega-kernel with the work-stealing bug fixed. R6 did
// atomicAdd per-THREAD (256 fetches/block/trip -> divergent tiles sharing
// one LDS stage -> garbage + unprocessed tiles -> inf). Now thread 0
// fetches, broadcasts via LDS; loop is block-uniform. All else = R6.

typedef __attribute__((ext_vector_type(8))) short short8;   // 8 x bf16
typedef __attribute__((ext_vector_type(4))) float f32x4;    // MFMA C/D

#define GPTR(p) (const __attribute__((address_space(1))) void*)(p)
#define LPTR(p) (__attribute__((address_space(3))) void*)(p)

constexpr int CB = 4, CS = 2048, CD = 768;
constexpr int CBS = CB * CS;            // 8192
constexpr int GRID = 1024;              // 4 blocks/CU on 256 CUs

__device__ inline unsigned short f2bf_bits(float v) {
    __hip_bfloat16 h = __float2bfloat16(v);
    unsigned short u;
    __builtin_memcpy(&u, &h, 2);
    return u;
}

__device__ inline ushort4 cvt4(float4 f) {
    ushort4 u;
    u.x = f2bf_bits(f.x); u.y = f2bf_bits(f.y);
    u.z = f2bf_bits(f.z); u.w = f2bf_bits(f.w);
    return u;
}

// ---------------------------------------------------------------------------
// Single-use grid barrier: count to gridDim, spin. Agent-scope fences
// replace the inter-dispatch L2 writeback/invalidate.
// ---------------------------------------------------------------------------
__device__ inline void grid_barrier(int* bar) {
    __threadfence();                    // release
    __syncthreads();
    if (threadIdx.x == 0) {
        __hip_atomic_fetch_add(bar, 1, __ATOMIC_ACQ_REL, __HIP_MEMORY_SCOPE_AGENT);
        while (__hip_atomic_load(bar, __ATOMIC_ACQUIRE, __HIP_MEMORY_SCOPE_AGENT)
               < (int)gridDim.x)
            __builtin_amdgcn_s_sleep(2);
    }
    __syncthreads();
    __threadfence();                    // acquire
}

// ---------------------------------------------------------------------------
// GEMM core: acc[MI][4] += A[m,k]*B[n,k]. BM x 128 tile, BK=64 (2x32 slabs).
// Both operands K-major, leading dim K. kend must be a multiple of 64.
// ---------------------------------------------------------------------------
template <int BM>
__device__ __forceinline__ void gemm_core(
    const __hip_bfloat16* __restrict__ A,
    const __hip_bfloat16* __restrict__ B,
    __hip_bfloat16* As, __hip_bfloat16* Bs,
    int m0, int n0, int K, int kend,
    f32x4 (&acc)[BM / 32][4])
{
    constexpr int AC = BM / 16;
    constexpr int SC = AC + 8;
    constexpr int MI = BM / 32;

    const int t  = threadIdx.x;
    const int w  = t >> 6;
    const int l  = t & 63;
    const int lq = l >> 4;
    const int lm = l & 15;
    const int wm = (w >> 1) * (BM / 2);
    const int wn = (w & 1) * 64;

    const int srow = l >> 2;
    const int scol = (l & 3) * 8;

    for (int k0 = 0; k0 < kend; k0 += 64) {
        __syncthreads();
#pragma unroll
        for (int ci = 0; ci < 2 * SC / 4; ++ci) {
            const int c    = ci * 4 + w;
            const int slab = (c >= SC) ? 1 : 0;
            const int cc   = c - slab * SC;
            const int kofs = k0 + slab * 32 + scol;
            if (cc < AC) {
                __builtin_amdgcn_global_load_lds(
                    GPTR(A + (size_t)(m0 + cc * 16 + srow) * K + kofs),
                    LPTR(&As[slab * BM * 32 + cc * 512]), 16, 0, 0);
            } else {
                const int c2 = cc - AC;
                __builtin_amdgcn_global_load_lds(
                    GPTR(B + (size_t)(n0 + c2 * 16 + srow) * K + kofs),
                    LPTR(&Bs[slab * 128 * 32 + c2 * 512]), 16, 0, 0);
            }
        }
        __syncthreads();

#pragma unroll
        for (int kk = 0; kk < 2; ++kk) {
            short8 af[MI], bf[4];
#pragma unroll
            for (int i = 0; i < MI; ++i)
                af[i] = *(const short8*)&As[kk * BM * 32 + (wm + i * 16 + lm) * 32 + lq * 8];
#pragma unroll
            for (int j = 0; j < 4; ++j)
                bf[j] = *(const short8*)&Bs[kk * 128 * 32 + (wn + j * 16 + lm) * 32 + lq * 8];

#pragma unroll
            for (int i = 0; i < MI; ++i)
#pragma unroll
                for (int j = 0; j < 4; ++j)
                    acc[i][j] = __builtin_amdgcn_mfma_f32_16x16x32_bf16(
                        af[i], bf[j], acc[i][j], 0, 0, 0);
        }
    }
}

template <int MI>
__device__ __forceinline__ void zero_acc(f32x4 (&acc)[MI][4]) {
#pragma unroll
    for (int i = 0; i < MI; ++i)
#pragma unroll
        for (int j = 0; j < 4; ++j)
            acc[i][j] = f32x4{0.f, 0.f, 0.f, 0.f};
}

// ---------------------------------------------------------------------------
// Mega-kernel. ctl[0..2] = barriers, ctl[3..5] = phase work counters.
// ---------------------------------------------------------------------------
__global__ __launch_bounds__(256, 4) void attn_mega(
    const float4* __restrict__ x,  const float4* __restrict__ wq,
    const float4* __restrict__ wk, const float4* __restrict__ wv,
    __hip_bfloat16* __restrict__ x16, __hip_bfloat16* __restrict__ w16,
    __hip_bfloat16* __restrict__ q16, __hip_bfloat16* __restrict__ k16,
    __hip_bfloat16* __restrict__ vt16, __hip_bfloat16* __restrict__ sp16,
    float* __restrict__ rowsum, int* __restrict__ ctl,
    float* __restrict__ out)
{
    __shared__ __align__(16) __hip_bfloat16 As[2 * 128 * 32];   // 16 KB
    __shared__ __align__(16) __hip_bfloat16 Bs[2 * 128 * 32];   // 16 KB
    __shared__ int s_id;

    const int t  = threadIdx.x;
    const int w  = t >> 6;
    const int l  = t & 63;
    const int lq = l >> 4;
    const int lm = l & 15;

    // ---- Phase 0: fp32->bf16 casts + rowsum zero (grid-stride) ----
    {
        constexpr int NX = CBS * CD / 4;
        constexpr int NW = CD * CD / 4;
        constexpr int NT = NX + 3 * NW;
        constexpr int NTOT = NT + CB * CS / 4;
        for (int i = blockIdx.x * 256 + t; i < NTOT; i += GRID * 256) {
            if (i < NX) {
                ((ushort4*)x16)[i] = cvt4(x[i]);
            } else if (i < NT) {
                const int j = i - NX;
                if (j < NW)          ((ushort4*)w16)[j] = cvt4(wq[j]);
                else if (j < 2 * NW) ((ushort4*)w16)[j] = cvt4(wk[j - NW]);
                else                 ((ushort4*)w16)[j] = cvt4(wv[j - 2 * NW]);
            } else {
                ((float4*)rowsum)[i - NT] = float4{0.f, 0.f, 0.f, 0.f};
            }
        }
    }
    grid_barrier(&ctl[0]);

    // ---- Phase 1: Q/K/Vt projections, 1152 tiles, block-level stealing ----
    for (;;) {
        __syncthreads();                         // protect s_id reuse
        if (t == 0) s_id = atomicAdd(&ctl[3], 1);
        __syncthreads();
        const int id = s_id;                     // block-uniform
        if (id >= 1152) break;

        const int wm = (w >> 1) * 64;
        const int wn = (w & 1) * 64;
        f32x4 acc[4][4];
        zero_acc<4>(acc);

        const __hip_bfloat16* A;
        const __hip_bfloat16* B;
        __hip_bfloat16* C;
        int m0, n0, ldc;
        if (id < 768) {
            const int proj = id / 384;          // 0=Q, 1=K
            const int r    = id % 384;
            n0 = (r % 6) * 128;
            m0 = (r / 6) * 128;
            A = x16; B = w16 + (size_t)proj * CD * CD;
            C = proj ? k16 : q16; ldc = CD;
        } else {
            int r = id - 768;
            const int b  = r / 96;  r %= 96;
            n0 = (r % 16) * 128;
            m0 = (r / 16) * 128;
            A = w16 + (size_t)2 * CD * CD;
            B = x16  + (size_t)b * CS * CD;
            C = vt16 + (size_t)b * CD * CS; ldc = CS;
        }

        gemm_core<128>(A, B, As, Bs, m0, n0, CD, CD, acc);

#pragma unroll
        for (int i = 0; i < 4; ++i)
#pragma unroll
            for (int j = 0; j < 4; ++j) {
                const int n = n0 + wn + j * 16 + lm;
#pragma unroll
                for (int r = 0; r < 4; ++r) {
                    const int m = m0 + wm + i * 16 + lq * 4 + r;
                    C[(size_t)m * ldc + n] = __float2bfloat16(acc[i][j][r]);
                }
            }
    }
    grid_barrier(&ctl[1]);

    // ---- Phase 2: E = exp(scale*QK^T) causal, rowsum atomics. 1088 tiles ----
    {
        const float scale = 0.03608439182435161f;
        for (;;) {
            __syncthreads();
            if (t == 0) s_id = atomicAdd(&ctl[4], 1);
            __syncthreads();
            const int g = s_id;
            if (g >= 1088) break;

            const int b  = g & 3;
            const int tt = g >> 2;              // 0..271
            int s = (int)sqrtf((float)tt);
            while ((s + 1) * (s + 1) <= tt) ++s;
            while (s * s > tt) --s;
            int mi, nj;
            if (tt < s * (s + 1)) { mi = 2 * s - 1; nj = tt - s * s; }
            else                  { mi = 2 * s;     nj = tt - s * (s + 1); }
            const int m0 = mi * 64;
            const int n0 = nj * 128;

            const __hip_bfloat16* A = q16 + (size_t)b * CS * CD;
            const __hip_bfloat16* B = k16 + (size_t)b * CS * CD;
            __hip_bfloat16* C = sp16 + (size_t)b * CS * CS;
            float* rs = rowsum + (size_t)b * CS;

            f32x4 acc[2][4];
            zero_acc<2>(acc);
            gemm_core<64>(A, B, As, Bs, m0, n0, CD, CD, acc);

            const int wm = (w >> 1) * 32;
            const int wn = (w & 1) * 64;
#pragma unroll
            for (int i = 0; i < 2; ++i) {
                float psum[4] = {0.f, 0.f, 0.f, 0.f};
#pragma unroll
                for (int j = 0; j < 4; ++j) {
                    const int n = n0 + wn + j * 16 + lm;
#pragma unroll
                    for (int r = 0; r < 4; ++r) {
                        const int m = m0 + wm + i * 16 + lq * 4 + r;
                        float e = (n <= m) ? __expf(acc[i][j][r] * scale) : 0.f;
                        C[(size_t)m * CS + n] = __float2bfloat16(e);
                        psum[r] += e;
                    }
                }
#pragma unroll
                for (int r = 0; r < 4; ++r) {
#pragma unroll
                    for (int off = 1; off < 16; off <<= 1)
                        psum[r] += __shfl_xor(psum[r], off);
                    if (lm == 0) {
                        const int m = m0 + wm + i * 16 + lq * 4 + r;
                        atomicAdd(&rs[m], psum[r]);
                    }
                }
            }
        }
    }
    grid_barrier(&ctl[2]);

    // ---- Phase 3: out = (E @ Vt^T)/rowsum, 768 tiles, LPT (heavy first) ----
    for (;;) {
        __syncthreads();
        if (t == 0) s_id = atomicAdd(&ctl[5], 1);
        __syncthreads();
        const int id = s_id;
        if (id >= 768) break;

        const int mrev = id / 24;
        int r          = id % 24;
        const int b    = r / 6;
        const int n0   = (r % 6) * 128;
        const int mi   = 31 - mrev;
        const int m0   = mi * 64;
        const int kend = m0 + 64;

        const __hip_bfloat16* A = sp16 + (size_t)b * CS * CS;
        const __hip_bfloat16* B = vt16 + (size_t)b * CD * CS;
        float* Co = out + (size_t)b * CS * CD;
        const float* rs = rowsum + (size_t)b * CS;

        f32x4 acc[2][4];
        zero_acc<2>(acc);
        gemm_core<64>(A, B, As, Bs, m0, n0, CS, kend, acc);

        const int wm = (w >> 1) * 32;
        const int wn = (w & 1) * 64;
#pragma unroll
        for (int i = 0; i < 2; ++i) {
            float inv[4];
#pragma unroll
            for (int r2 = 0; r2 < 4; ++r2)
                inv[r2] = 1.0f / rs[m0 + wm + i * 16 + lq * 4 + r2];
#pragma unroll
            for (int j = 0; j < 4; ++j) {
                const int n = n0 + wn + j * 16 + lm;
#pragma unroll
                for (int r2 = 0; r2 < 4; ++r2) {
                    const int m = m0 + wm + i * 16 + lq * 4 + r2;
                    Co[(size_t)m * CD + n] = acc[i][j][r2] * inv[r2];
                }
            }
        }
    }
}

// ---------------------------------------------------------------------------
// Launch
// ---------------------------------------------------------------------------
extern "C" void kernel_launch(void* const* d_in, const int* in_sizes, int n_in,
                              void* d_out, int out_size, void* d_ws, size_t ws_size,
                              hipStream_t stream)
{
    const float* x  = (const float*)d_in[0];
    const float* Wq = (const float*)d_in[1];
    const float* Wk = (const float*)d_in[2];
    const float* Wv = (const float*)d_in[3];
    float* out = (float*)d_out;

    char* ws = (char*)d_ws;
    size_t off = 0;
    auto alloc = [&](size_t bytes) { char* p = ws + off; off += bytes; return p; };

    __hip_bfloat16* x16  = (__hip_bfloat16*)alloc((size_t)CBS * CD * 2);
    __hip_bfloat16* q16  = (__hip_bfloat16*)alloc((size_t)CBS * CD * 2);
    __hip_bfloat16* k16  = (__hip_bfloat16*)alloc((size_t)CBS * CD * 2);
    __hip_bfloat16* vt16 = (__hip_bfloat16*)alloc((size_t)CBS * CD * 2);   // [B][D][S]
    __hip_bfloat16* sp16 = (__hip_bfloat16*)alloc((size_t)CB * CS * CS * 2);
    __hip_bfloat16* w16  = (__hip_bfloat16*)alloc((size_t)3 * CD * CD * 2);
    float*          rsum = (float*)alloc((size_t)CB * CS * sizeof(float));
    int*            ctl  = (int*)alloc(64);

    hipMemsetAsync(ctl, 0, 6 * sizeof(int), stream);

    attn_mega<<<GRID, 256, 0, stream>>>(
        (const float4*)x, (const float4*)Wq, (const float4*)Wk, (const float4*)Wv,
        x16, w16, q16, k16, vt16, sp16, rsum, ctl, out);
}

// Round 8
// 1105.148 us; speedup vs baseline: 1.2011x; 1.2011x over previous
//
#include <hip/hip_runtime.h>
#include <hip/hip_bf16.h>
#include <cstdint>
#include <cstddef>

// B=4, S=2048, D=768 single-head causal attention, fp32 I/O.
// Round 8: mega-kernel, spill fixed. R7's __launch_bounds__(256,4) forced
// combined VGPR+AGPR <= 128 vs ~148 needed -> K-loop scratch spills (VGPR
// 84->64, FETCH +120MB, MfmaUtil 1.6%, 7x). Now: natural regalloc, and
// sync made residency-independent (work-stealing + done-counters instead of
// count-to-gridDim barriers), so no occupancy guarantee is required.

typedef __attribute__((ext_vector_type(8))) short short8;   // 8 x bf16
typedef __attribute__((ext_vector_type(4))) float f32x4;    // MFMA C/D

#define GPTR(p) (const __attribute__((address_space(1))) void*)(p)
#define LPTR(p) (__attribute__((address_space(3))) void*)(p)

constexpr int CB = 4, CS = 2048, CD = 768;
constexpr int CBS = CB * CS;            // 8192
constexpr int GRID = 1024;

// phase work totals
constexpr int NX0   = CBS * CD / 4;                 // x float4 groups
constexpr int NW0   = CD * CD / 4;                  // one W float4 groups
constexpr int NTOT0 = NX0 + 3 * NW0 + CB * CS / 4;  // + rowsum zeroing
constexpr int NC0   = (NTOT0 + 8191) / 8192;        // 8192-item chunks
constexpr int NT1   = 1152;                          // qkv tiles
constexpr int NT2   = 1088;                          // score tiles
constexpr int NT3   = 768;                           // pv tiles

__device__ inline unsigned short f2bf_bits(float v) {
    __hip_bfloat16 h = __float2bfloat16(v);
    unsigned short u;
    __builtin_memcpy(&u, &h, 2);
    return u;
}

__device__ inline ushort4 cvt4(float4 f) {
    ushort4 u;
    u.x = f2bf_bits(f.x); u.y = f2bf_bits(f.y);
    u.z = f2bf_bits(f.z); u.w = f2bf_bits(f.w);
    return u;
}

// ---------------------------------------------------------------------------
// Residency-independent phase sync: workers add their tile count (release),
// everyone waits for done == target (acquire). Any subset of resident blocks
// can finish a phase; late blocks steal nothing and fall through.
// ---------------------------------------------------------------------------
__device__ inline void finish_phase(int* done, int cnt) {
    __threadfence();                    // release own stores (L2 writeback)
    __syncthreads();                    // order all threads' fences before add
    if (threadIdx.x == 0 && cnt)
        __hip_atomic_fetch_add(done, cnt, __ATOMIC_RELEASE,
                               __HIP_MEMORY_SCOPE_AGENT);
}

__device__ inline void wait_done(int* done, int target) {
    if (threadIdx.x == 0) {
        while (__hip_atomic_load(done, __ATOMIC_ACQUIRE,
                                 __HIP_MEMORY_SCOPE_AGENT) < target)
            __builtin_amdgcn_s_sleep(8);
    }
    __syncthreads();
    __threadfence();                    // invalidate stale cached lines
}

// ---------------------------------------------------------------------------
// GEMM core: acc[MI][4] += A[m,k]*B[n,k]. BM x 128 tile, BK=64 (2x32 slabs).
// Both operands K-major, leading dim K. kend must be a multiple of 64.
// ---------------------------------------------------------------------------
template <int BM>
__device__ __forceinline__ void gemm_core(
    const __hip_bfloat16* __restrict__ A,
    const __hip_bfloat16* __restrict__ B,
    __hip_bfloat16* As, __hip_bfloat16* Bs,
    int m0, int n0, int K, int kend,
    f32x4 (&acc)[BM / 32][4])
{
    constexpr int AC = BM / 16;
    constexpr int SC = AC + 8;
    constexpr int MI = BM / 32;

    const int t  = threadIdx.x;
    const int w  = t >> 6;
    const int l  = t & 63;
    const int lq = l >> 4;
    const int lm = l & 15;
    const int wm = (w >> 1) * (BM / 2);
    const int wn = (w & 1) * 64;

    const int srow = l >> 2;
    const int scol = (l & 3) * 8;

    for (int k0 = 0; k0 < kend; k0 += 64) {
        __syncthreads();
#pragma unroll
        for (int ci = 0; ci < 2 * SC / 4; ++ci) {
            const int c    = ci * 4 + w;
            const int slab = (c >= SC) ? 1 : 0;
            const int cc   = c - slab * SC;
            const int kofs = k0 + slab * 32 + scol;
            if (cc < AC) {
                __builtin_amdgcn_global_load_lds(
                    GPTR(A + (size_t)(m0 + cc * 16 + srow) * K + kofs),
                    LPTR(&As[slab * BM * 32 + cc * 512]), 16, 0, 0);
            } else {
                const int c2 = cc - AC;
                __builtin_amdgcn_global_load_lds(
                    GPTR(B + (size_t)(n0 + c2 * 16 + srow) * K + kofs),
                    LPTR(&Bs[slab * 128 * 32 + c2 * 512]), 16, 0, 0);
            }
        }
        __syncthreads();

#pragma unroll
        for (int kk = 0; kk < 2; ++kk) {
            short8 af[MI], bf[4];
#pragma unroll
            for (int i = 0; i < MI; ++i)
                af[i] = *(const short8*)&As[kk * BM * 32 + (wm + i * 16 + lm) * 32 + lq * 8];
#pragma unroll
            for (int j = 0; j < 4; ++j)
                bf[j] = *(const short8*)&Bs[kk * 128 * 32 + (wn + j * 16 + lm) * 32 + lq * 8];

#pragma unroll
            for (int i = 0; i < MI; ++i)
#pragma unroll
                for (int j = 0; j < 4; ++j)
                    acc[i][j] = __builtin_amdgcn_mfma_f32_16x16x32_bf16(
                        af[i], bf[j], acc[i][j], 0, 0, 0);
        }
    }
}

template <int MI>
__device__ __forceinline__ void zero_acc(f32x4 (&acc)[MI][4]) {
#pragma unroll
    for (int i = 0; i < MI; ++i)
#pragma unroll
        for (int j = 0; j < 4; ++j)
            acc[i][j] = f32x4{0.f, 0.f, 0.f, 0.f};
}

// ---------------------------------------------------------------------------
// Mega-kernel. ctl: [0]=steal0 [1]=done0 [2]=steal1 [3]=done1
//                   [4]=steal2 [5]=done2 [6]=steal3 (memset 0)
// ---------------------------------------------------------------------------
__global__ __launch_bounds__(256) void attn_mega(
    const float4* __restrict__ x,  const float4* __restrict__ wq,
    const float4* __restrict__ wk, const float4* __restrict__ wv,
    __hip_bfloat16* __restrict__ x16, __hip_bfloat16* __restrict__ w16,
    __hip_bfloat16* __restrict__ q16, __hip_bfloat16* __restrict__ k16,
    __hip_bfloat16* __restrict__ vt16, __hip_bfloat16* __restrict__ sp16,
    float* __restrict__ rowsum, int* __restrict__ ctl,
    float* __restrict__ out)
{
    __shared__ __align__(16) __hip_bfloat16 As[2 * 128 * 32];   // 16 KB
    __shared__ __align__(16) __hip_bfloat16 Bs[2 * 128 * 32];   // 16 KB
    __shared__ int s_id;

    const int t  = threadIdx.x;
    const int w  = t >> 6;
    const int l  = t & 63;
    const int lq = l >> 4;
    const int lm = l & 15;

    // ---- Phase 0: casts + rowsum zero, stolen 8192-item chunks ----
    {
        int cnt = 0;
        for (;;) {
            __syncthreads();
            if (t == 0) s_id = atomicAdd(&ctl[0], 1);
            __syncthreads();
            const int c = s_id;
            if (c >= NC0) break;
            const int base = c * 8192;
#pragma unroll
            for (int k2 = 0; k2 < 32; ++k2) {
                const int i = base + k2 * 256 + t;
                if (i >= NTOT0) break;
                if (i < NX0) {
                    ((ushort4*)x16)[i] = cvt4(x[i]);
                } else if (i < NX0 + 3 * NW0) {
                    const int j = i - NX0;
                    if (j < NW0)          ((ushort4*)w16)[j] = cvt4(wq[j]);
                    else if (j < 2 * NW0) ((ushort4*)w16)[j] = cvt4(wk[j - NW0]);
                    else                  ((ushort4*)w16)[j] = cvt4(wv[j - 2 * NW0]);
                } else {
                    ((float4*)rowsum)[i - NX0 - 3 * NW0] = float4{0.f, 0.f, 0.f, 0.f};
                }
            }
            ++cnt;
        }
        finish_phase(&ctl[1], cnt);
        wait_done(&ctl[1], NC0);
    }

    // ---- Phase 1: Q/K/Vt projections, 1152 tiles ----
    {
        int cnt = 0;
        for (;;) {
            __syncthreads();
            if (t == 0) s_id = atomicAdd(&ctl[2], 1);
            __syncthreads();
            const int id = s_id;
            if (id >= NT1) break;

            const int wm = (w >> 1) * 64;
            const int wn = (w & 1) * 64;
            f32x4 acc[4][4];
            zero_acc<4>(acc);

            const __hip_bfloat16* A;
            const __hip_bfloat16* B;
            __hip_bfloat16* C;
            int m0, n0, ldc;
            if (id < 768) {
                const int proj = id / 384;      // 0=Q, 1=K
                const int r    = id % 384;
                n0 = (r % 6) * 128;
                m0 = (r / 6) * 128;
                A = x16; B = w16 + (size_t)proj * CD * CD;
                C = proj ? k16 : q16; ldc = CD;
            } else {
                int r = id - 768;
                const int b  = r / 96;  r %= 96;
                n0 = (r % 16) * 128;
                m0 = (r / 16) * 128;
                A = w16 + (size_t)2 * CD * CD;
                B = x16  + (size_t)b * CS * CD;
                C = vt16 + (size_t)b * CD * CS; ldc = CS;
            }

            gemm_core<128>(A, B, As, Bs, m0, n0, CD, CD, acc);

#pragma unroll
            for (int i = 0; i < 4; ++i)
#pragma unroll
                for (int j = 0; j < 4; ++j) {
                    const int n = n0 + wn + j * 16 + lm;
#pragma unroll
                    for (int r = 0; r < 4; ++r) {
                        const int m = m0 + wm + i * 16 + lq * 4 + r;
                        C[(size_t)m * ldc + n] = __float2bfloat16(acc[i][j][r]);
                    }
                }
            ++cnt;
        }
        finish_phase(&ctl[3], cnt);
        wait_done(&ctl[3], NT1);
    }

    // ---- Phase 2: E = exp(scale*QK^T) causal + rowsum atomics, 1088 tiles ----
    {
        const float scale = 0.03608439182435161f;
        int cnt = 0;
        for (;;) {
            __syncthreads();
            if (t == 0) s_id = atomicAdd(&ctl[4], 1);
            __syncthreads();
            const int g = s_id;
            if (g >= NT2) break;

            const int b  = g & 3;
            const int tt = g >> 2;              // 0..271
            int s = (int)sqrtf((float)tt);
            while ((s + 1) * (s + 1) <= tt) ++s;
            while (s * s > tt) --s;
            int mi, nj;
            if (tt < s * (s + 1)) { mi = 2 * s - 1; nj = tt - s * s; }
            else                  { mi = 2 * s;     nj = tt - s * (s + 1); }
            const int m0 = mi * 64;
            const int n0 = nj * 128;

            const __hip_bfloat16* A = q16 + (size_t)b * CS * CD;
            const __hip_bfloat16* B = k16 + (size_t)b * CS * CD;
            __hip_bfloat16* C = sp16 + (size_t)b * CS * CS;
            float* rs = rowsum + (size_t)b * CS;

            f32x4 acc[2][4];
            zero_acc<2>(acc);
            gemm_core<64>(A, B, As, Bs, m0, n0, CD, CD, acc);

            const int wm = (w >> 1) * 32;
            const int wn = (w & 1) * 64;
#pragma unroll
            for (int i = 0; i < 2; ++i) {
                float psum[4] = {0.f, 0.f, 0.f, 0.f};
#pragma unroll
                for (int j = 0; j < 4; ++j) {
                    const int n = n0 + wn + j * 16 + lm;
#pragma unroll
                    for (int r = 0; r < 4; ++r) {
                        const int m = m0 + wm + i * 16 + lq * 4 + r;
                        float e = (n <= m) ? __expf(acc[i][j][r] * scale) : 0.f;
                        C[(size_t)m * CS + n] = __float2bfloat16(e);
                        psum[r] += e;
                    }
                }
#pragma unroll
                for (int r = 0; r < 4; ++r) {
#pragma unroll
                    for (int off = 1; off < 16; off <<= 1)
                        psum[r] += __shfl_xor(psum[r], off);
                    if (lm == 0) {
                        const int m = m0 + wm + i * 16 + lq * 4 + r;
                        atomicAdd(&rs[m], psum[r]);
                    }
                }
            }
            ++cnt;
        }
        finish_phase(&ctl[5], cnt);
        wait_done(&ctl[5], NT2);
    }

    // ---- Phase 3: out = (E @ Vt^T)/rowsum, 768 tiles, LPT heavy-first ----
    for (;;) {
        __syncthreads();
        if (t == 0) s_id = atomicAdd(&ctl[6], 1);
        __syncthreads();
        const int id = s_id;
        if (id >= NT3) break;

        const int mrev = id / 24;
        int r          = id % 24;
        const int b    = r / 6;
        const int n0   = (r % 6) * 128;
        const int mi   = 31 - mrev;
        const int m0   = mi * 64;
        const int kend = m0 + 64;

        const __hip_bfloat16* A = sp16 + (size_t)b * CS * CS;
        const __hip_bfloat16* B = vt16 + (size_t)b * CD * CS;
        float* Co = out + (size_t)b * CS * CD;
        const float* rs = rowsum + (size_t)b * CS;

        f32x4 acc[2][4];
        zero_acc<2>(acc);
        gemm_core<64>(A, B, As, Bs, m0, n0, CS, kend, acc);

        const int wm = (w >> 1) * 32;
        const int wn = (w & 1) * 64;
#pragma unroll
        for (int i = 0; i < 2; ++i) {
            float inv[4];
#pragma unroll
            for (int r2 = 0; r2 < 4; ++r2)
                inv[r2] = 1.0f / rs[m0 + wm + i * 16 + lq * 4 + r2];
#pragma unroll
            for (int j = 0; j < 4; ++j) {
                const int n = n0 + wn + j * 16 + lm;
#pragma unroll
                for (int r2 = 0; r2 < 4; ++r2) {
                    const int m = m0 + wm + i * 16 + lq * 4 + r2;
                    Co[(size_t)m * CD + n] = acc[i][j][r2] * inv[r2];
                }
            }
        }
    }
}

// ---------------------------------------------------------------------------
// Launch
// ---------------------------------------------------------------------------
extern "C" void kernel_launch(void* const* d_in, const int* in_sizes, int n_in,
                              void* d_out, int out_size, void* d_ws, size_t ws_size,
                              hipStream_t stream)
{
    const float* x  = (const float*)d_in[0];
    const float* Wq = (const float*)d_in[1];
    const float* Wk = (const float*)d_in[2];
    const float* Wv = (const float*)d_in[3];
    float* out = (float*)d_out;

    char* ws = (char*)d_ws;
    size_t off = 0;
    auto alloc = [&](size_t bytes) { char* p = ws + off; off += bytes; return p; };

    __hip_bfloat16* x16  = (__hip_bfloat16*)alloc((size_t)CBS * CD * 2);
    __hip_bfloat16* q16  = (__hip_bfloat16*)alloc((size_t)CBS * CD * 2);
    __hip_bfloat16* k16  = (__hip_bfloat16*)alloc((size_t)CBS * CD * 2);
    __hip_bfloat16* vt16 = (__hip_bfloat16*)alloc((size_t)CBS * CD * 2);   // [B][D][S]
    __hip_bfloat16* sp16 = (__hip_bfloat16*)alloc((size_t)CB * CS * CS * 2);
    __hip_bfloat16* w16  = (__hip_bfloat16*)alloc((size_t)3 * CD * CD * 2);
    float*          rsum = (float*)alloc((size_t)CB * CS * sizeof(float));
    int*            ctl  = (int*)alloc(64);

    hipMemsetAsync(ctl, 0, 8 * sizeof(int), stream);

    attn_mega<<<GRID, 256, 0, stream>>>(
        (const float4*)x, (const float4*)Wq, (const float4*)Wk, (const float4*)Wv,
        x16, w16, q16, k16, vt16, sp16, rsum, ctl, out);
}

// Round 9
// 196.205 us; speedup vs baseline: 6.7652x; 5.6326x over previous
//
#include <hip/hip_runtime.h>
#include <hip/hip_bf16.h>
#include <cstdint>
#include <cstddef>

// B=4, S=2048, D=768 single-head causal attention, fp32 I/O.
// Round 9: revert to R5 multi-dispatch (mega-kernel R6-R8 disproven: per-block
// agent fences = per-block L2 writeback/invalidate on non-coherent XCD L2s ->
// permanently cold L2, 6x slower). One change vs R5: scores at BM=128 compact
// (544 triangular tiles; 2x FLOP/staged-byte, 321->214 MB staged).

typedef __attribute__((ext_vector_type(8))) short short8;   // 8 x bf16
typedef __attribute__((ext_vector_type(4))) float f32x4;    // MFMA C/D

#define GPTR(p) (const __attribute__((address_space(1))) void*)(p)
#define LPTR(p) (__attribute__((address_space(3))) void*)(p)

constexpr int CB = 4, CS = 2048, CD = 768;
constexpr int CBS = CB * CS;            // 8192

__device__ inline unsigned short f2bf_bits(float v) {
    __hip_bfloat16 h = __float2bfloat16(v);
    unsigned short u;
    __builtin_memcpy(&u, &h, 2);
    return u;
}

__device__ inline ushort4 cvt4(float4 f) {
    ushort4 u;
    u.x = f2bf_bits(f.x); u.y = f2bf_bits(f.y);
    u.z = f2bf_bits(f.z); u.w = f2bf_bits(f.w);
    return u;
}

// ---------------------------------------------------------------------------
// single cast dispatch: x -> x16, Wq|Wk|Wv -> w16, and zero rowsum.
// ---------------------------------------------------------------------------
__global__ __launch_bounds__(256) void cvt_all(
    const float4* __restrict__ x,  const float4* __restrict__ wq,
    const float4* __restrict__ wk, const float4* __restrict__ wv,
    ushort4* __restrict__ x16, ushort4* __restrict__ w16,
    float4* __restrict__ rsum4)
{
    constexpr int NX = CBS * CD / 4;        // 1572864
    constexpr int NW = CD * CD / 4;         // 147456
    constexpr int NT = NX + 3 * NW;         // 2015232
    const int i = blockIdx.x * 256 + threadIdx.x;
    if (i < NX) {
        x16[i] = cvt4(x[i]);
    } else if (i < NT) {
        const int j = i - NX;
        if (j < NW)            w16[j] = cvt4(wq[j]);
        else if (j < 2 * NW)   w16[j] = cvt4(wk[j - NW]);
        else                   w16[j] = cvt4(wv[j - 2 * NW]);
    } else {
        const int j = i - NT;               // 0..2047 : zero rowsum
        rsum4[j] = float4{0.f, 0.f, 0.f, 0.f};
    }
}

// ---------------------------------------------------------------------------
// GEMM core: acc[MI][4] += A[m,k]*B[n,k]. BM x 128 tile, BK=64 (2x32 slabs).
// Both operands K-major, leading dim K. kend must be a multiple of 64.
// LDS: As[2][BM][32], Bs[2][128][32] -- slab s holds k-cols k0+s*32..+31.
// ---------------------------------------------------------------------------
template <int BM>
__device__ __forceinline__ void gemm_core(
    const __hip_bfloat16* __restrict__ A,
    const __hip_bfloat16* __restrict__ B,
    __hip_bfloat16* As, __hip_bfloat16* Bs,
    int m0, int n0, int K, int kend,
    f32x4 (&acc)[BM / 32][4])
{
    constexpr int AC = BM / 16;     // A chunks per slab
    constexpr int SC = AC + 8;      // chunks per slab (A + 8 B chunks)
    constexpr int MI = BM / 32;

    const int t  = threadIdx.x;
    const int w  = t >> 6;
    const int l  = t & 63;
    const int lq = l >> 4;
    const int lm = l & 15;
    const int wm = (w >> 1) * (BM / 2);
    const int wn = (w & 1) * 64;

    const int srow = l >> 2;
    const int scol = (l & 3) * 8;

    for (int k0 = 0; k0 < kend; k0 += 64) {
        __syncthreads();
#pragma unroll
        for (int ci = 0; ci < 2 * SC / 4; ++ci) {
            const int c    = ci * 4 + w;
            const int slab = (c >= SC) ? 1 : 0;
            const int cc   = c - slab * SC;
            const int kofs = k0 + slab * 32 + scol;
            if (cc < AC) {
                __builtin_amdgcn_global_load_lds(
                    GPTR(A + (size_t)(m0 + cc * 16 + srow) * K + kofs),
                    LPTR(&As[slab * BM * 32 + cc * 512]), 16, 0, 0);
            } else {
                const int c2 = cc - AC;
                __builtin_amdgcn_global_load_lds(
                    GPTR(B + (size_t)(n0 + c2 * 16 + srow) * K + kofs),
                    LPTR(&Bs[slab * 128 * 32 + c2 * 512]), 16, 0, 0);
            }
        }
        __syncthreads();

#pragma unroll
        for (int kk = 0; kk < 2; ++kk) {
            short8 af[MI], bf[4];
#pragma unroll
            for (int i = 0; i < MI; ++i)
                af[i] = *(const short8*)&As[kk * BM * 32 + (wm + i * 16 + lm) * 32 + lq * 8];
#pragma unroll
            for (int j = 0; j < 4; ++j)
                bf[j] = *(const short8*)&Bs[kk * 128 * 32 + (wn + j * 16 + lm) * 32 + lq * 8];

#pragma unroll
            for (int i = 0; i < MI; ++i)
#pragma unroll
                for (int j = 0; j < 4; ++j)
                    acc[i][j] = __builtin_amdgcn_mfma_f32_16x16x32_bf16(
                        af[i], bf[j], acc[i][j], 0, 0, 0);
        }
    }
}

template <int MI>
__device__ __forceinline__ void zero_acc(f32x4 (&acc)[MI][4]) {
#pragma unroll
    for (int i = 0; i < MI; ++i)
#pragma unroll
        for (int j = 0; j < 4; ++j)
            acc[i][j] = f32x4{0.f, 0.f, 0.f, 0.f};
}

// ---------------------------------------------------------------------------
// Fused Q/K/Vt projections: 1152 uniform blocks (K=768, 12 BK-iters).
// ---------------------------------------------------------------------------
__global__ __launch_bounds__(256) void qkv_gemm(
    const __hip_bfloat16* __restrict__ x16,
    const __hip_bfloat16* __restrict__ w16,
    __hip_bfloat16* __restrict__ q16,
    __hip_bfloat16* __restrict__ k16,
    __hip_bfloat16* __restrict__ vt16)
{
    __shared__ __align__(16) __hip_bfloat16 As[2 * 128 * 32];   // 16 KB
    __shared__ __align__(16) __hip_bfloat16 Bs[2 * 128 * 32];   // 16 KB

    const int t  = threadIdx.x;
    const int w  = t >> 6;
    const int l  = t & 63;
    const int lq = l >> 4;
    const int lm = l & 15;
    const int wm = (w >> 1) * 64;
    const int wn = (w & 1) * 64;

    f32x4 acc[4][4];
    zero_acc<4>(acc);

    const __hip_bfloat16* A;
    const __hip_bfloat16* B;
    __hip_bfloat16* C;
    int m0, n0, ldc;

    const int id = blockIdx.x;
    if (id < 768) {
        const int proj = id / 384;              // 0=Q, 1=K
        const int r    = id % 384;
        n0 = (r % 6) * 128;
        m0 = (r / 6) * 128;
        A = x16; B = w16 + (size_t)proj * CD * CD;
        C = proj ? k16 : q16; ldc = CD;
    } else {
        int r = id - 768;
        const int b  = r / 96;  r %= 96;
        n0 = (r % 16) * 128;
        m0 = (r / 16) * 128;
        A = w16 + (size_t)2 * CD * CD;
        B = x16  + (size_t)b * CS * CD;
        C = vt16 + (size_t)b * CD * CS; ldc = CS;
    }

    gemm_core<128>(A, B, As, Bs, m0, n0, CD, CD, acc);

#pragma unroll
    for (int i = 0; i < 4; ++i)
#pragma unroll
        for (int j = 0; j < 4; ++j) {
            const int n = n0 + wn + j * 16 + lm;
#pragma unroll
            for (int r = 0; r < 4; ++r) {
                const int m = m0 + wm + i * 16 + lq * 4 + r;
                C[(size_t)m * ldc + n] = __float2bfloat16(acc[i][j][r]);
            }
        }
}

// ---------------------------------------------------------------------------
// E[b] = exp(scale * Q[b] @ K[b]^T), causal, BM=128 x BN=128 COMPACT grid:
// 544 tiles = 4 batches x 136 triangular (mi 0..15, nj 0..mi).
// Per-row sums accumulated into rowsum via fp32 atomics.
// ---------------------------------------------------------------------------
__global__ __launch_bounds__(256) void scores_gemm(
    const __hip_bfloat16* __restrict__ q16,
    const __hip_bfloat16* __restrict__ k16,
    __hip_bfloat16* __restrict__ sp16,
    float* __restrict__ rowsum,
    float scale)
{
    const int g  = blockIdx.x;          // 0..543
    const int b  = g & 3;
    const int tt = g >> 2;              // 0..135 triangular index
    int mi = (int)((sqrtf(8.0f * tt + 1.0f) - 1.0f) * 0.5f);
    while ((mi + 1) * (mi + 2) / 2 <= tt) ++mi;
    while (mi * (mi + 1) / 2 > tt) --mi;
    const int nj = tt - mi * (mi + 1) / 2;
    const int m0 = mi * 128;
    const int n0 = nj * 128;

    __shared__ __align__(16) __hip_bfloat16 As[2 * 128 * 32];   // 16 KB
    __shared__ __align__(16) __hip_bfloat16 Bs[2 * 128 * 32];   // 16 KB

    const __hip_bfloat16* A = q16 + (size_t)b * CS * CD;
    const __hip_bfloat16* B = k16 + (size_t)b * CS * CD;
    __hip_bfloat16* C = sp16 + (size_t)b * CS * CS;
    float* rs = rowsum + (size_t)b * CS;

    f32x4 acc[4][4];
    zero_acc<4>(acc);
    gemm_core<128>(A, B, As, Bs, m0, n0, CD, CD, acc);

    const int t  = threadIdx.x;
    const int w  = t >> 6;
    const int l  = t & 63;
    const int lq = l >> 4;
    const int lm = l & 15;
    const int wm = (w >> 1) * 64;
    const int wn = (w & 1) * 64;

#pragma unroll
    for (int i = 0; i < 4; ++i) {
        float psum[4] = {0.f, 0.f, 0.f, 0.f};
#pragma unroll
        for (int j = 0; j < 4; ++j) {
            const int n = n0 + wn + j * 16 + lm;
#pragma unroll
            for (int r = 0; r < 4; ++r) {
                const int m = m0 + wm + i * 16 + lq * 4 + r;
                float e = (n <= m) ? __expf(acc[i][j][r] * scale) : 0.f;
                C[(size_t)m * CS + n] = __float2bfloat16(e);
                psum[r] += e;
            }
        }
#pragma unroll
        for (int r = 0; r < 4; ++r) {
#pragma unroll
            for (int off = 1; off < 16; off <<= 1)
                psum[r] += __shfl_xor(psum[r], off);
            if (lm == 0) {
                const int m = m0 + wm + i * 16 + lq * 4 + r;
                atomicAdd(&rs[m], psum[r]);
            }
        }
    }
}

// ---------------------------------------------------------------------------
// out[b] = (E[b] @ Vt[b]^T) / rowsum, 64x128 tiles, kend = m0+64,
// heavy-first (LPT) ordering.  (unchanged from R5)
// ---------------------------------------------------------------------------
__global__ __launch_bounds__(256) void pv_gemm(
    const __hip_bfloat16* __restrict__ sp16,
    const __hip_bfloat16* __restrict__ vt16,
    const float* __restrict__ rowsum,
    float* __restrict__ out)
{
    const int id   = blockIdx.x;        // 0..767
    const int mrev = id / 24;
    int r          = id % 24;
    const int b    = r / 6;
    const int n0   = (r % 6) * 128;
    const int mi   = 31 - mrev;         // heavy (large kend) first
    const int m0   = mi * 64;
    const int kend = m0 + 64;

    __shared__ __align__(16) __hip_bfloat16 As[2 * 64 * 32];    // 8 KB
    __shared__ __align__(16) __hip_bfloat16 Bs[2 * 128 * 32];   // 16 KB

    const __hip_bfloat16* A = sp16 + (size_t)b * CS * CS;
    const __hip_bfloat16* B = vt16 + (size_t)b * CD * CS;
    float* Co = out + (size_t)b * CS * CD;
    const float* rs = rowsum + (size_t)b * CS;

    f32x4 acc[2][4];
    zero_acc<2>(acc);
    gemm_core<64>(A, B, As, Bs, m0, n0, CS, kend, acc);

    const int t  = threadIdx.x;
    const int w  = t >> 6;
    const int l  = t & 63;
    const int lq = l >> 4;
    const int lm = l & 15;
    const int wm = (w >> 1) * 32;
    const int wn = (w & 1) * 64;

#pragma unroll
    for (int i = 0; i < 2; ++i) {
        float inv[4];
#pragma unroll
        for (int r2 = 0; r2 < 4; ++r2)
            inv[r2] = 1.0f / rs[m0 + wm + i * 16 + lq * 4 + r2];
#pragma unroll
        for (int j = 0; j < 4; ++j) {
            const int n = n0 + wn + j * 16 + lm;
#pragma unroll
            for (int r2 = 0; r2 < 4; ++r2) {
                const int m = m0 + wm + i * 16 + lq * 4 + r2;
                Co[(size_t)m * CD + n] = acc[i][j][r2] * inv[r2];
            }
        }
    }
}

// ---------------------------------------------------------------------------
// Launch
// ---------------------------------------------------------------------------
extern "C" void kernel_launch(void* const* d_in, const int* in_sizes, int n_in,
                              void* d_out, int out_size, void* d_ws, size_t ws_size,
                              hipStream_t stream)
{
    const float* x  = (const float*)d_in[0];
    const float* Wq = (const float*)d_in[1];
    const float* Wk = (const float*)d_in[2];
    const float* Wv = (const float*)d_in[3];
    float* out = (float*)d_out;

    char* ws = (char*)d_ws;
    size_t off = 0;
    auto alloc = [&](size_t bytes) { char* p = ws + off; off += bytes; return p; };

    __hip_bfloat16* x16  = (__hip_bfloat16*)alloc((size_t)CBS * CD * 2);
    __hip_bfloat16* q16  = (__hip_bfloat16*)alloc((size_t)CBS * CD * 2);
    __hip_bfloat16* k16  = (__hip_bfloat16*)alloc((size_t)CBS * CD * 2);
    __hip_bfloat16* vt16 = (__hip_bfloat16*)alloc((size_t)CBS * CD * 2);   // [B][D][S]
    __hip_bfloat16* sp16 = (__hip_bfloat16*)alloc((size_t)CB * CS * CS * 2);
    __hip_bfloat16* w16  = (__hip_bfloat16*)alloc((size_t)3 * CD * CD * 2);
    float*          rsum = (float*)alloc((size_t)CB * CS * sizeof(float));

    // cvt grid: 7872 blocks of conversions + 8 blocks zeroing rsum
    constexpr int NCVT_BLK = (CBS * CD + 3 * CD * CD) / 4 / 256 + 8;
    cvt_all<<<NCVT_BLK, 256, 0, stream>>>(
        (const float4*)x, (const float4*)Wq, (const float4*)Wk, (const float4*)Wv,
        (ushort4*)x16, (ushort4*)w16, (float4*)rsum);

    qkv_gemm<<<1152, 256, 0, stream>>>(x16, w16, q16, k16, vt16);

    scores_gemm<<<544, 256, 0, stream>>>(
        q16, k16, sp16, rsum, 0.03608439182435161f);

    pv_gemm<<<768, 256, 0, stream>>>(sp16, vt16, rsum, out);
}

// Round 10
// 195.054 us; speedup vs baseline: 6.8052x; 1.0059x over previous
//
#include <hip/hip_runtime.h>
#include <hip/hip_bf16.h>
#include <cstdint>
#include <cstddef>

// B=4, S=2048, D=768 single-head causal attention, fp32 I/O.
// Round 10: resident-block model (rate ~ 5.2 B/cyc/CU per resident block,
// capped by min(grid/256, regs, LDS)). Scores back to proven BM=64 compact.
// qkv -> BM=64 (2304 blocks, 6/CU residency vs 3). pv -> BN=64 (1536 blocks).

typedef __attribute__((ext_vector_type(8))) short short8;   // 8 x bf16
typedef __attribute__((ext_vector_type(4))) float f32x4;    // MFMA C/D

#define GPTR(p) (const __attribute__((address_space(1))) void*)(p)
#define LPTR(p) (__attribute__((address_space(3))) void*)(p)

constexpr int CB = 4, CS = 2048, CD = 768;
constexpr int CBS = CB * CS;            // 8192

__device__ inline unsigned short f2bf_bits(float v) {
    __hip_bfloat16 h = __float2bfloat16(v);
    unsigned short u;
    __builtin_memcpy(&u, &h, 2);
    return u;
}

__device__ inline ushort4 cvt4(float4 f) {
    ushort4 u;
    u.x = f2bf_bits(f.x); u.y = f2bf_bits(f.y);
    u.z = f2bf_bits(f.z); u.w = f2bf_bits(f.w);
    return u;
}

// ---------------------------------------------------------------------------
// single cast dispatch: x -> x16, Wq|Wk|Wv -> w16, and zero rowsum.
// ---------------------------------------------------------------------------
__global__ __launch_bounds__(256) void cvt_all(
    const float4* __restrict__ x,  const float4* __restrict__ wq,
    const float4* __restrict__ wk, const float4* __restrict__ wv,
    ushort4* __restrict__ x16, ushort4* __restrict__ w16,
    float4* __restrict__ rsum4)
{
    constexpr int NX = CBS * CD / 4;        // 1572864
    constexpr int NW = CD * CD / 4;         // 147456
    constexpr int NT = NX + 3 * NW;         // 2015232
    const int i = blockIdx.x * 256 + threadIdx.x;
    if (i < NX) {
        x16[i] = cvt4(x[i]);
    } else if (i < NT) {
        const int j = i - NX;
        if (j < NW)            w16[j] = cvt4(wq[j]);
        else if (j < 2 * NW)   w16[j] = cvt4(wk[j - NW]);
        else                   w16[j] = cvt4(wv[j - 2 * NW]);
    } else {
        const int j = i - NT;               // zero rowsum (8192 f32)
        rsum4[j] = float4{0.f, 0.f, 0.f, 0.f};
    }
}

// ---------------------------------------------------------------------------
// GEMM core: acc[MI][4] += A[m,k]*B[n,k]. BM x BN tile, BK=64 (2x32 slabs).
// Both operands K-major, leading dim K. kend must be a multiple of 64.
// Wave tiling: BN=128 -> 2x2 waves (wave n-span 64); BN=64 -> 4x1 waves.
// ---------------------------------------------------------------------------
template <int BM, int BN>
__device__ __forceinline__ void gemm_core(
    const __hip_bfloat16* __restrict__ A,
    const __hip_bfloat16* __restrict__ B,
    __hip_bfloat16* As, __hip_bfloat16* Bs,
    int m0, int n0, int K, int kend,
    f32x4 (&acc)[BM / (16 * ((BN == 128) ? 2 : 4))][4])
{
    constexpr int AC = BM / 16;         // A chunks per slab
    constexpr int BC = BN / 16;         // B chunks per slab
    constexpr int SC = AC + BC;
    constexpr int WM = (BN == 128) ? 2 : 4;
    constexpr int MI = BM / (16 * WM);

    const int t  = threadIdx.x;
    const int w  = t >> 6;
    const int l  = t & 63;
    const int lq = l >> 4;
    const int lm = l & 15;
    const int wmi = (WM == 2) ? (w >> 1) : w;
    const int wni = (WM == 2) ? (w & 1) : 0;
    const int wm = wmi * (16 * MI);
    const int wn = wni * 64;

    const int srow = l >> 2;
    const int scol = (l & 3) * 8;

    for (int k0 = 0; k0 < kend; k0 += 64) {
        __syncthreads();
#pragma unroll
        for (int ci = 0; ci < 2 * SC / 4; ++ci) {
            const int c    = ci * 4 + w;
            const int slab = (c >= SC) ? 1 : 0;
            const int cc   = c - slab * SC;
            const int kofs = k0 + slab * 32 + scol;
            if (cc < AC) {
                __builtin_amdgcn_global_load_lds(
                    GPTR(A + (size_t)(m0 + cc * 16 + srow) * K + kofs),
                    LPTR(&As[slab * BM * 32 + cc * 512]), 16, 0, 0);
            } else {
                const int c2 = cc - AC;
                __builtin_amdgcn_global_load_lds(
                    GPTR(B + (size_t)(n0 + c2 * 16 + srow) * K + kofs),
                    LPTR(&Bs[slab * BN * 32 + c2 * 512]), 16, 0, 0);
            }
        }
        __syncthreads();

#pragma unroll
        for (int kk = 0; kk < 2; ++kk) {
            short8 af[MI], bf[4];
#pragma unroll
            for (int i = 0; i < MI; ++i)
                af[i] = *(const short8*)&As[kk * BM * 32 + (wm + i * 16 + lm) * 32 + lq * 8];
#pragma unroll
            for (int j = 0; j < 4; ++j)
                bf[j] = *(const short8*)&Bs[kk * BN * 32 + (wn + j * 16 + lm) * 32 + lq * 8];

#pragma unroll
            for (int i = 0; i < MI; ++i)
#pragma unroll
                for (int j = 0; j < 4; ++j)
                    acc[i][j] = __builtin_amdgcn_mfma_f32_16x16x32_bf16(
                        af[i], bf[j], acc[i][j], 0, 0, 0);
        }
    }
}

template <int MI>
__device__ __forceinline__ void zero_acc(f32x4 (&acc)[MI][4]) {
#pragma unroll
    for (int i = 0; i < MI; ++i)
#pragma unroll
        for (int j = 0; j < 4; ++j)
            acc[i][j] = f32x4{0.f, 0.f, 0.f, 0.f};
}

// ---------------------------------------------------------------------------
// Fused Q/K/Vt projections, BM=64: 2304 uniform blocks (K=768, 12 BK-iters).
//   id 0..767    : Q tiles  (m 128 x6 n)
//   id 768..1535 : K tiles
//   id 1536..2303: Vt tiles (per-batch, m = D/64 = 12, n = S/128 = 16)
// ---------------------------------------------------------------------------
__global__ __launch_bounds__(256) void qkv_gemm(
    const __hip_bfloat16* __restrict__ x16,
    const __hip_bfloat16* __restrict__ w16,
    __hip_bfloat16* __restrict__ q16,
    __hip_bfloat16* __restrict__ k16,
    __hip_bfloat16* __restrict__ vt16)
{
    __shared__ __align__(16) __hip_bfloat16 As[2 * 64 * 32];    // 8 KB
    __shared__ __align__(16) __hip_bfloat16 Bs[2 * 128 * 32];   // 16 KB

    const int t  = threadIdx.x;
    const int w  = t >> 6;
    const int l  = t & 63;
    const int lq = l >> 4;
    const int lm = l & 15;
    const int wm = (w >> 1) * 32;
    const int wn = (w & 1) * 64;

    f32x4 acc[2][4];
    zero_acc<2>(acc);

    const __hip_bfloat16* A;
    const __hip_bfloat16* B;
    __hip_bfloat16* C;
    int m0, n0, ldc;

    const int id = blockIdx.x;
    if (id < 1536) {
        const int proj = id / 768;              // 0=Q, 1=K
        const int r    = id % 768;
        n0 = (r % 6) * 128;
        m0 = (r / 6) * 64;
        A = x16; B = w16 + (size_t)proj * CD * CD;
        C = proj ? k16 : q16; ldc = CD;
    } else {
        int r = id - 1536;
        const int b  = r / 192;  r %= 192;
        n0 = (r % 16) * 128;
        m0 = (r / 16) * 64;
        A = w16 + (size_t)2 * CD * CD;
        B = x16  + (size_t)b * CS * CD;
        C = vt16 + (size_t)b * CD * CS; ldc = CS;
    }

    gemm_core<64, 128>(A, B, As, Bs, m0, n0, CD, CD, acc);

#pragma unroll
    for (int i = 0; i < 2; ++i)
#pragma unroll
        for (int j = 0; j < 4; ++j) {
            const int n = n0 + wn + j * 16 + lm;
#pragma unroll
            for (int r = 0; r < 4; ++r) {
                const int m = m0 + wm + i * 16 + lq * 4 + r;
                C[(size_t)m * ldc + n] = __float2bfloat16(acc[i][j][r]);
            }
        }
}

// ---------------------------------------------------------------------------
// E[b] = exp(scale * Q[b] @ K[b]^T), causal, 64x128 tiles, COMPACT 1088 grid
// (R5-proven). Per-row sums accumulated into rowsum via fp32 atomics.
// ---------------------------------------------------------------------------
__global__ __launch_bounds__(256) void scores_gemm(
    const __hip_bfloat16* __restrict__ q16,
    const __hip_bfloat16* __restrict__ k16,
    __hip_bfloat16* __restrict__ sp16,
    float* __restrict__ rowsum,
    float scale)
{
    const int g  = blockIdx.x;          // 0..1087
    const int b  = g & 3;
    const int tt = g >> 2;              // 0..271
    int s = (int)sqrtf((float)tt);
    while ((s + 1) * (s + 1) <= tt) ++s;
    while (s * s > tt) --s;
    int mi, nj;
    if (tt < s * (s + 1)) { mi = 2 * s - 1; nj = tt - s * s; }
    else                  { mi = 2 * s;     nj = tt - s * (s + 1); }
    const int m0 = mi * 64;
    const int n0 = nj * 128;

    __shared__ __align__(16) __hip_bfloat16 As[2 * 64 * 32];    // 8 KB
    __shared__ __align__(16) __hip_bfloat16 Bs[2 * 128 * 32];   // 16 KB

    const __hip_bfloat16* A = q16 + (size_t)b * CS * CD;
    const __hip_bfloat16* B = k16 + (size_t)b * CS * CD;
    __hip_bfloat16* C = sp16 + (size_t)b * CS * CS;
    float* rs = rowsum + (size_t)b * CS;

    f32x4 acc[2][4];
    zero_acc<2>(acc);
    gemm_core<64, 128>(A, B, As, Bs, m0, n0, CD, CD, acc);

    const int t  = threadIdx.x;
    const int w  = t >> 6;
    const int l  = t & 63;
    const int lq = l >> 4;
    const int lm = l & 15;
    const int wm = (w >> 1) * 32;
    const int wn = (w & 1) * 64;

#pragma unroll
    for (int i = 0; i < 2; ++i) {
        float psum[4] = {0.f, 0.f, 0.f, 0.f};
#pragma unroll
        for (int j = 0; j < 4; ++j) {
            const int n = n0 + wn + j * 16 + lm;
#pragma unroll
            for (int r = 0; r < 4; ++r) {
                const int m = m0 + wm + i * 16 + lq * 4 + r;
                float e = (n <= m) ? __expf(acc[i][j][r] * scale) : 0.f;
                C[(size_t)m * CS + n] = __float2bfloat16(e);
                psum[r] += e;
            }
        }
#pragma unroll
        for (int r = 0; r < 4; ++r) {
#pragma unroll
            for (int off = 1; off < 16; off <<= 1)
                psum[r] += __shfl_xor(psum[r], off);
            if (lm == 0) {
                const int m = m0 + wm + i * 16 + lq * 4 + r;
                atomicAdd(&rs[m], psum[r]);
            }
        }
    }
}

// ---------------------------------------------------------------------------
// out[b] = (E[b] @ Vt[b]^T) / rowsum, 64x64 tiles (BN=64 -> 1536 blocks,
// 6/CU), kend = m0+64, heavy-first (LPT) ordering.
// ---------------------------------------------------------------------------
__global__ __launch_bounds__(256) void pv_gemm(
    const __hip_bfloat16* __restrict__ sp16,
    const __hip_bfloat16* __restrict__ vt16,
    const float* __restrict__ rowsum,
    float* __restrict__ out)
{
    const int id   = blockIdx.x;        // 0..1535
    const int mrev = id / 48;
    int r          = id % 48;
    const int b    = r / 12;
    const int n0   = (r % 12) * 64;
    const int mi   = 31 - mrev;         // heavy (large kend) first
    const int m0   = mi * 64;
    const int kend = m0 + 64;

    __shared__ __align__(16) __hip_bfloat16 As[2 * 64 * 32];    // 8 KB
    __shared__ __align__(16) __hip_bfloat16 Bs[2 * 64 * 32];    // 8 KB

    const __hip_bfloat16* A = sp16 + (size_t)b * CS * CS;
    const __hip_bfloat16* B = vt16 + (size_t)b * CD * CS;
    float* Co = out + (size_t)b * CS * CD;
    const float* rs = rowsum + (size_t)b * CS;

    f32x4 acc[1][4];
    zero_acc<1>(acc);
    gemm_core<64, 64>(A, B, As, Bs, m0, n0, CS, kend, acc);

    const int t  = threadIdx.x;
    const int w  = t >> 6;
    const int l  = t & 63;
    const int lq = l >> 4;
    const int lm = l & 15;
    const int wm = w * 16;              // 4x1 wave tiling

    float inv[4];
#pragma unroll
    for (int r2 = 0; r2 < 4; ++r2)
        inv[r2] = 1.0f / rs[m0 + wm + lq * 4 + r2];
#pragma unroll
    for (int j = 0; j < 4; ++j) {
        const int n = n0 + j * 16 + lm;
#pragma unroll
        for (int r2 = 0; r2 < 4; ++r2) {
            const int m = m0 + wm + lq * 4 + r2;
            Co[(size_t)m * CD + n] = acc[0][j][r2] * inv[r2];
        }
    }
}

// ---------------------------------------------------------------------------
// Launch
// ---------------------------------------------------------------------------
extern "C" void kernel_launch(void* const* d_in, const int* in_sizes, int n_in,
                              void* d_out, int out_size, void* d_ws, size_t ws_size,
                              hipStream_t stream)
{
    const float* x  = (const float*)d_in[0];
    const float* Wq = (const float*)d_in[1];
    const float* Wk = (const float*)d_in[2];
    const float* Wv = (const float*)d_in[3];
    float* out = (float*)d_out;

    char* ws = (char*)d_ws;
    size_t off = 0;
    auto alloc = [&](size_t bytes) { char* p = ws + off; off += bytes; return p; };

    __hip_bfloat16* x16  = (__hip_bfloat16*)alloc((size_t)CBS * CD * 2);
    __hip_bfloat16* q16  = (__hip_bfloat16*)alloc((size_t)CBS * CD * 2);
    __hip_bfloat16* k16  = (__hip_bfloat16*)alloc((size_t)CBS * CD * 2);
    __hip_bfloat16* vt16 = (__hip_bfloat16*)alloc((size_t)CBS * CD * 2);   // [B][D][S]
    __hip_bfloat16* sp16 = (__hip_bfloat16*)alloc((size_t)CB * CS * CS * 2);
    __hip_bfloat16* w16  = (__hip_bfloat16*)alloc((size_t)3 * CD * CD * 2);
    float*          rsum = (float*)alloc((size_t)CB * CS * sizeof(float));

    constexpr int NCVT_BLK = (CBS * CD + 3 * CD * CD) / 4 / 256 + 8;
    cvt_all<<<NCVT_BLK, 256, 0, stream>>>(
        (const float4*)x, (const float4*)Wq, (const float4*)Wk, (const float4*)Wv,
        (ushort4*)x16, (ushort4*)w16, (float4*)rsum);

    qkv_gemm<<<2304, 256, 0, stream>>>(x16, w16, q16, k16, vt16);

    scores_gemm<<<1088, 256, 0, stream>>>(
        q16, k16, sp16, rsum, 0.03608439182435161f);

    pv_gemm<<<1536, 256, 0, stream>>>(sp16, vt16, rsum, out);
}